// Round 4
// baseline (179.613 us; speedup 1.0000x reference)
//
#include <hip/hip_runtime.h>

#define T_LEN 1024
#define NSTEP 1023
#define SPT   16     // steps per thread: 64 lanes x 16 = 1024 >= 1023

// Affine semigroup element: state action R+=V*tau + C*r; V+=C*v; C=C*M.
struct El {
    float c0,c1,c2,c3,c4,c5,c6,c7,c8;   // M (row-major)
    float v0,v1,v2;
    float r0,r1,r2;
    float tau;
};

// a = earlier segment, b = later segment; returns a∘b
__device__ __forceinline__ El compose(const El& a, const El& b) {
    El o;
    o.r0 = a.r0 + a.v0*b.tau + a.c0*b.r0 + a.c1*b.r1 + a.c2*b.r2;
    o.r1 = a.r1 + a.v1*b.tau + a.c3*b.r0 + a.c4*b.r1 + a.c5*b.r2;
    o.r2 = a.r2 + a.v2*b.tau + a.c6*b.r0 + a.c7*b.r1 + a.c8*b.r2;
    o.v0 = a.v0 + a.c0*b.v0 + a.c1*b.v1 + a.c2*b.v2;
    o.v1 = a.v1 + a.c3*b.v0 + a.c4*b.v1 + a.c5*b.v2;
    o.v2 = a.v2 + a.c6*b.v0 + a.c7*b.v1 + a.c8*b.v2;
    o.c0 = a.c0*b.c0 + a.c1*b.c3 + a.c2*b.c6;
    o.c1 = a.c0*b.c1 + a.c1*b.c4 + a.c2*b.c7;
    o.c2 = a.c0*b.c2 + a.c1*b.c5 + a.c2*b.c8;
    o.c3 = a.c3*b.c0 + a.c4*b.c3 + a.c5*b.c6;
    o.c4 = a.c3*b.c1 + a.c4*b.c4 + a.c5*b.c7;
    o.c5 = a.c3*b.c2 + a.c4*b.c5 + a.c5*b.c8;
    o.c6 = a.c6*b.c0 + a.c7*b.c3 + a.c8*b.c6;
    o.c7 = a.c6*b.c1 + a.c7*b.c4 + a.c8*b.c7;
    o.c8 = a.c6*b.c2 + a.c7*b.c5 + a.c8*b.c8;
    o.tau = a.tau + b.tau;
    return o;
}

__device__ __forceinline__ El shfl_down_el(const El& e, int delta) {
    El o;
    o.c0 = __shfl_down(e.c0, delta);
    o.c1 = __shfl_down(e.c1, delta);
    o.c2 = __shfl_down(e.c2, delta);
    o.c3 = __shfl_down(e.c3, delta);
    o.c4 = __shfl_down(e.c4, delta);
    o.c5 = __shfl_down(e.c5, delta);
    o.c6 = __shfl_down(e.c6, delta);
    o.c7 = __shfl_down(e.c7, delta);
    o.c8 = __shfl_down(e.c8, delta);
    o.v0 = __shfl_down(e.v0, delta);
    o.v1 = __shfl_down(e.v1, delta);
    o.v2 = __shfl_down(e.v2, delta);
    o.r0 = __shfl_down(e.r0, delta);
    o.r1 = __shfl_down(e.r1, delta);
    o.r2 = __shfl_down(e.r2, delta);
    o.tau = __shfl_down(e.tau, delta);
    return o;
}

__device__ __forceinline__ void so3_exp(float px, float py, float pz, float R[9]) {
    float t2 = px*px + py*py + pz*pz;
    float A, Bc;
    if (t2 < 1e-2f) {
        // Taylor: exact to ~1e-10 rel for theta < 0.1 (our theta <= ~0.02)
        float t4 = t2*t2;
        A  = 1.0f - t2*(1.0f/6.0f)  + t4*(1.0f/120.0f);
        Bc = 0.5f - t2*(1.0f/24.0f) + t4*(1.0f/720.0f);
    } else {
        float th = sqrtf(t2);
        A = __sinf(th)/th;
        float sh = __sinf(0.5f*th);
        Bc = 2.0f*sh*sh/t2;   // (1-cos)/t2 without cancellation
    }
    float xx = px*px, yy = py*py, zz = pz*pz;
    float xy = px*py, xz = px*pz, yz = py*pz;
    R[0] = 1.0f - Bc*(yy+zz);
    R[1] = Bc*xy - A*pz;
    R[2] = Bc*xz + A*py;
    R[3] = Bc*xy + A*pz;
    R[4] = 1.0f - Bc*(xx+zz);
    R[5] = Bc*yz - A*px;
    R[6] = Bc*xz - A*py;
    R[7] = Bc*yz + A*px;
    R[8] = 1.0f - Bc*(xx+yy);
}

// One WAVE per batch row (4 rows per 256-thread block).
// No __syncthreads, no LDS: wave-internal adjacent-pair shuffle tree.
extern "C" __global__ void __launch_bounds__(256)
rmi_kernel(const float* __restrict__ x, float* __restrict__ out, int B) {
    const int lane = threadIdx.x & 63;
    const int wid  = threadIdx.x >> 6;
    const int b    = blockIdx.x * 4 + wid;
    if (b >= B) return;
    const float* __restrict__ xb = x + (size_t)b * (7 * T_LEN);
    const int k0 = lane * SPT;

    El e = {1.f,0.f,0.f, 0.f,1.f,0.f, 0.f,0.f,1.f,
            0.f,0.f,0.f, 0.f,0.f,0.f, 0.f};

#pragma unroll
    for (int c = 0; c < SPT/4; ++c) {
        const int kc = k0 + 4*c;
        float4 t4  = *reinterpret_cast<const float4*>(xb + kc);
        float  tn  = (kc + 4 < T_LEN) ? xb[kc + 4] : 0.0f;
        float4 wx4 = *reinterpret_cast<const float4*>(xb + 1*T_LEN + kc);
        float4 wy4 = *reinterpret_cast<const float4*>(xb + 2*T_LEN + kc);
        float4 wz4 = *reinterpret_cast<const float4*>(xb + 3*T_LEN + kc);
        float4 ax4 = *reinterpret_cast<const float4*>(xb + 4*T_LEN + kc);
        float4 ay4 = *reinterpret_cast<const float4*>(xb + 5*T_LEN + kc);
        float4 az4 = *reinterpret_cast<const float4*>(xb + 6*T_LEN + kc);

        float tv[5]  = {t4.x, t4.y, t4.z, t4.w, tn};
        float wxv[4] = {wx4.x, wx4.y, wx4.z, wx4.w};
        float wyv[4] = {wy4.x, wy4.y, wy4.z, wy4.w};
        float wzv[4] = {wz4.x, wz4.y, wz4.z, wz4.w};
        float axv[4] = {ax4.x, ax4.y, ax4.z, ax4.w};
        float ayv[4] = {ay4.x, ay4.y, ay4.z, ay4.w};
        float azv[4] = {az4.x, az4.y, az4.z, az4.w};

#pragma unroll
        for (int j = 0; j < 4; ++j) {
            const int k = kc + j;
            if (k < NSTEP) {
                float dt = tv[j+1] - tv[j];
                float ax = axv[j], ay = ayv[j], az = azv[j];
                float Ca0 = e.c0*ax + e.c1*ay + e.c2*az;
                float Ca1 = e.c3*ax + e.c4*ay + e.c5*az;
                float Ca2 = e.c6*ax + e.c7*ay + e.c8*az;
                float h = 0.5f * dt * dt;
                e.r0 += e.v0*dt + Ca0*h;
                e.r1 += e.v1*dt + Ca1*h;
                e.r2 += e.v2*dt + Ca2*h;
                e.v0 += Ca0*dt;
                e.v1 += Ca1*dt;
                e.v2 += Ca2*dt;
                float Rk[9];
                so3_exp(wxv[j]*dt, wyv[j]*dt, wzv[j]*dt, Rk);
                float n0 = e.c0*Rk[0] + e.c1*Rk[3] + e.c2*Rk[6];
                float n1 = e.c0*Rk[1] + e.c1*Rk[4] + e.c2*Rk[7];
                float n2 = e.c0*Rk[2] + e.c1*Rk[5] + e.c2*Rk[8];
                float n3 = e.c3*Rk[0] + e.c4*Rk[3] + e.c5*Rk[6];
                float n4 = e.c3*Rk[1] + e.c4*Rk[4] + e.c5*Rk[7];
                float n5 = e.c3*Rk[2] + e.c4*Rk[5] + e.c5*Rk[8];
                float n6 = e.c6*Rk[0] + e.c7*Rk[3] + e.c8*Rk[6];
                float n7 = e.c6*Rk[1] + e.c7*Rk[4] + e.c8*Rk[7];
                float n8 = e.c6*Rk[2] + e.c7*Rk[5] + e.c8*Rk[8];
                e.c0=n0; e.c1=n1; e.c2=n2;
                e.c3=n3; e.c4=n4; e.c5=n5;
                e.c6=n6; e.c7=n7; e.c8=n8;
                e.tau += dt;
            }
        }
    }

    // ---- wave-internal adjacent-pair tree (order-preserving) ----
    // After level str, lanes with lane % (2*str) == 0 hold exact [lane, lane+2*str).
    // Other lanes hold garbage that is never consumed by an aligned lane.
#pragma unroll
    for (int str = 1; str < 64; str <<= 1) {
        El o = shfl_down_el(e, str);
        e = compose(e, o);
    }

    if (lane == 0) {
        float* ob = out + (size_t)b * 15;
        ob[0]=e.c0;  ob[1]=e.c1;  ob[2]=e.c2;
        ob[3]=e.c3;  ob[4]=e.c4;  ob[5]=e.c5;
        ob[6]=e.c6;  ob[7]=e.c7;  ob[8]=e.c8;
        ob[9]=e.v0;  ob[10]=e.v1; ob[11]=e.v2;
        ob[12]=e.r0; ob[13]=e.r1; ob[14]=e.r2;
    }
}

extern "C" void kernel_launch(void* const* d_in, const int* in_sizes, int n_in,
                              void* d_out, int out_size, void* d_ws, size_t ws_size,
                              hipStream_t stream) {
    const float* x = (const float*)d_in[0];
    float* out = (float*)d_out;
    const int B = in_sizes[0] / (7 * T_LEN);   // 4096
    rmi_kernel<<<(B + 3) / 4, 256, 0, stream>>>(x, out, B);
}

// Round 5
// 165.831 us; speedup vs baseline: 1.0831x; 1.0831x over previous
//
#include <hip/hip_runtime.h>

#define T_LEN 1024
#define NSTEP 1023

// Affine semigroup element: state action R+=V*tau + C*r; V+=C*v; C=C*M.
struct El {
    float c0,c1,c2,c3,c4,c5,c6,c7,c8;   // M (row-major)
    float v0,v1,v2;
    float r0,r1,r2;
    float tau;
};

// a = earlier segment, b = later segment; returns a∘b
__device__ __forceinline__ El compose(const El& a, const El& b) {
    El o;
    o.r0 = a.r0 + a.v0*b.tau + a.c0*b.r0 + a.c1*b.r1 + a.c2*b.r2;
    o.r1 = a.r1 + a.v1*b.tau + a.c3*b.r0 + a.c4*b.r1 + a.c5*b.r2;
    o.r2 = a.r2 + a.v2*b.tau + a.c6*b.r0 + a.c7*b.r1 + a.c8*b.r2;
    o.v0 = a.v0 + a.c0*b.v0 + a.c1*b.v1 + a.c2*b.v2;
    o.v1 = a.v1 + a.c3*b.v0 + a.c4*b.v1 + a.c5*b.v2;
    o.v2 = a.v2 + a.c6*b.v0 + a.c7*b.v1 + a.c8*b.v2;
    o.c0 = a.c0*b.c0 + a.c1*b.c3 + a.c2*b.c6;
    o.c1 = a.c0*b.c1 + a.c1*b.c4 + a.c2*b.c7;
    o.c2 = a.c0*b.c2 + a.c1*b.c5 + a.c2*b.c8;
    o.c3 = a.c3*b.c0 + a.c4*b.c3 + a.c5*b.c6;
    o.c4 = a.c3*b.c1 + a.c4*b.c4 + a.c5*b.c7;
    o.c5 = a.c3*b.c2 + a.c4*b.c5 + a.c5*b.c8;
    o.c6 = a.c6*b.c0 + a.c7*b.c3 + a.c8*b.c6;
    o.c7 = a.c6*b.c1 + a.c7*b.c4 + a.c8*b.c7;
    o.c8 = a.c6*b.c2 + a.c7*b.c5 + a.c8*b.c8;
    o.tau = a.tau + b.tau;
    return o;
}

__device__ __forceinline__ El shfl_down_el(const El& e, int delta) {
    El o;
    o.c0 = __shfl_down(e.c0, delta);
    o.c1 = __shfl_down(e.c1, delta);
    o.c2 = __shfl_down(e.c2, delta);
    o.c3 = __shfl_down(e.c3, delta);
    o.c4 = __shfl_down(e.c4, delta);
    o.c5 = __shfl_down(e.c5, delta);
    o.c6 = __shfl_down(e.c6, delta);
    o.c7 = __shfl_down(e.c7, delta);
    o.c8 = __shfl_down(e.c8, delta);
    o.v0 = __shfl_down(e.v0, delta);
    o.v1 = __shfl_down(e.v1, delta);
    o.v2 = __shfl_down(e.v2, delta);
    o.r0 = __shfl_down(e.r0, delta);
    o.r1 = __shfl_down(e.r1, delta);
    o.r2 = __shfl_down(e.r2, delta);
    o.tau = __shfl_down(e.tau, delta);
    return o;
}

__device__ __forceinline__ void so3_exp(float px, float py, float pz, float R[9]) {
    float t2 = px*px + py*py + pz*pz;
    float A, Bc;
    if (t2 < 1e-2f) {
        // Taylor: exact to ~1e-10 rel for theta < 0.1 (our theta <= ~0.02)
        float t4 = t2*t2;
        A  = 1.0f - t2*(1.0f/6.0f)  + t4*(1.0f/120.0f);
        Bc = 0.5f - t2*(1.0f/24.0f) + t4*(1.0f/720.0f);
    } else {
        float th = sqrtf(t2);
        A = __sinf(th)/th;
        float sh = __sinf(0.5f*th);
        Bc = 2.0f*sh*sh/t2;   // (1-cos)/t2 without cancellation
    }
    float xx = px*px, yy = py*py, zz = pz*pz;
    float xy = px*py, xz = px*pz, yz = py*pz;
    R[0] = 1.0f - Bc*(yy+zz);
    R[1] = Bc*xy - A*pz;
    R[2] = Bc*xz + A*py;
    R[3] = Bc*xy + A*pz;
    R[4] = 1.0f - Bc*(xx+zz);
    R[5] = Bc*yz - A*px;
    R[6] = Bc*xz - A*py;
    R[7] = Bc*yz + A*px;
    R[8] = 1.0f - Bc*(xx+yy);
}

// One BLOCK per batch row, 256 threads x 4 steps (coalesced float4 loads:
// lane-contiguous 16B => 1KB per wave load instruction).
// Reduction: 6-level wave-internal shfl tree (no barriers, all lanes active)
// -> 4 wave elements -> 1 __syncthreads -> thread 0 composes serially.
extern "C" __global__ void __launch_bounds__(256)
rmi_kernel(const float* __restrict__ x, float* __restrict__ out) {
    const int tid  = threadIdx.x;
    const int lane = tid & 63;
    const int wid  = tid >> 6;
    const int b    = blockIdx.x;
    const float* __restrict__ xb = x + (size_t)b * (7 * T_LEN);

    __shared__ float s[4 * 17];   // one El per wave, padded

    // ---- coalesced loads: 4 consecutive steps per thread ----
    const int k0 = tid * 4;
    float4 t4  = *reinterpret_cast<const float4*>(xb + k0);
    float  tn  = (k0 + 4 < T_LEN) ? xb[k0 + 4] : 0.0f;
    float4 wx4 = *reinterpret_cast<const float4*>(xb + 1*T_LEN + k0);
    float4 wy4 = *reinterpret_cast<const float4*>(xb + 2*T_LEN + k0);
    float4 wz4 = *reinterpret_cast<const float4*>(xb + 3*T_LEN + k0);
    float4 ax4 = *reinterpret_cast<const float4*>(xb + 4*T_LEN + k0);
    float4 ay4 = *reinterpret_cast<const float4*>(xb + 5*T_LEN + k0);
    float4 az4 = *reinterpret_cast<const float4*>(xb + 6*T_LEN + k0);

    float tv[5]  = {t4.x, t4.y, t4.z, t4.w, tn};
    float wxv[4] = {wx4.x, wx4.y, wx4.z, wx4.w};
    float wyv[4] = {wy4.x, wy4.y, wy4.z, wy4.w};
    float wzv[4] = {wz4.x, wz4.y, wz4.z, wz4.w};
    float axv[4] = {ax4.x, ax4.y, ax4.z, ax4.w};
    float ayv[4] = {ay4.x, ay4.y, ay4.z, ay4.w};
    float azv[4] = {az4.x, az4.y, az4.z, az4.w};

    El e = {1.f,0.f,0.f, 0.f,1.f,0.f, 0.f,0.f,1.f,
            0.f,0.f,0.f, 0.f,0.f,0.f, 0.f};

#pragma unroll
    for (int j = 0; j < 4; ++j) {
        const int k = k0 + j;
        if (k < NSTEP) {
            float dt = tv[j+1] - tv[j];
            float ax = axv[j], ay = ayv[j], az = azv[j];
            float Ca0 = e.c0*ax + e.c1*ay + e.c2*az;
            float Ca1 = e.c3*ax + e.c4*ay + e.c5*az;
            float Ca2 = e.c6*ax + e.c7*ay + e.c8*az;
            float h = 0.5f * dt * dt;
            e.r0 += e.v0*dt + Ca0*h;
            e.r1 += e.v1*dt + Ca1*h;
            e.r2 += e.v2*dt + Ca2*h;
            e.v0 += Ca0*dt;
            e.v1 += Ca1*dt;
            e.v2 += Ca2*dt;
            float Rk[9];
            so3_exp(wxv[j]*dt, wyv[j]*dt, wzv[j]*dt, Rk);
            float n0 = e.c0*Rk[0] + e.c1*Rk[3] + e.c2*Rk[6];
            float n1 = e.c0*Rk[1] + e.c1*Rk[4] + e.c2*Rk[7];
            float n2 = e.c0*Rk[2] + e.c1*Rk[5] + e.c2*Rk[8];
            float n3 = e.c3*Rk[0] + e.c4*Rk[3] + e.c5*Rk[6];
            float n4 = e.c3*Rk[1] + e.c4*Rk[4] + e.c5*Rk[7];
            float n5 = e.c3*Rk[2] + e.c4*Rk[5] + e.c5*Rk[8];
            float n6 = e.c6*Rk[0] + e.c7*Rk[3] + e.c8*Rk[6];
            float n7 = e.c6*Rk[1] + e.c7*Rk[4] + e.c8*Rk[7];
            float n8 = e.c6*Rk[2] + e.c7*Rk[5] + e.c8*Rk[8];
            e.c0=n0; e.c1=n1; e.c2=n2;
            e.c3=n3; e.c4=n4; e.c5=n5;
            e.c6=n6; e.c7=n7; e.c8=n8;
            e.tau += dt;
        }
    }

    // ---- wave-internal adjacent-pair tree (order-preserving, no barriers).
    // After level str, lanes with lane % (2*str) == 0 hold exact [lane, lane+2*str)
    // (in 4-step chunks); other lanes compute garbage never consumed by lane 0.
#pragma unroll
    for (int str = 1; str < 64; str <<= 1) {
        El o = shfl_down_el(e, str);
        e = compose(e, o);
    }

    // ---- combine the 4 wave elements ----
    if (lane == 0) {
        float* me = s + wid * 17;
        me[0]=e.c0;  me[1]=e.c1;  me[2]=e.c2;
        me[3]=e.c3;  me[4]=e.c4;  me[5]=e.c5;
        me[6]=e.c6;  me[7]=e.c7;  me[8]=e.c8;
        me[9]=e.v0;  me[10]=e.v1; me[11]=e.v2;
        me[12]=e.r0; me[13]=e.r1; me[14]=e.r2;
        me[15]=e.tau;
    }
    __syncthreads();
    if (tid == 0) {
#pragma unroll
        for (int w = 1; w < 4; ++w) {
            const float* o = s + w * 17;
            El q = {o[0],o[1],o[2],o[3],o[4],o[5],o[6],o[7],o[8],
                    o[9],o[10],o[11],o[12],o[13],o[14],o[15]};
            e = compose(e, q);
        }
        float* ob = out + (size_t)b * 15;
        ob[0]=e.c0;  ob[1]=e.c1;  ob[2]=e.c2;
        ob[3]=e.c3;  ob[4]=e.c4;  ob[5]=e.c5;
        ob[6]=e.c6;  ob[7]=e.c7;  ob[8]=e.c8;
        ob[9]=e.v0;  ob[10]=e.v1; ob[11]=e.v2;
        ob[12]=e.r0; ob[13]=e.r1; ob[14]=e.r2;
    }
}

extern "C" void kernel_launch(void* const* d_in, const int* in_sizes, int n_in,
                              void* d_out, int out_size, void* d_ws, size_t ws_size,
                              hipStream_t stream) {
    const float* x = (const float*)d_in[0];
    float* out = (float*)d_out;
    const int B = in_sizes[0] / (7 * T_LEN);   // 4096
    rmi_kernel<<<B, 256, 0, stream>>>(x, out);
}